// Round 1
// baseline (17188.432 us; speedup 1.0000x reference)
//
#include <hip/hip_runtime.h>
#include <hip/hip_bf16.h>

// LSTM persistent-kernel implementation for MI355X.
// T=2048 sequential steps; 64 WGs (1/CU), each owns 4 h-columns (16 gate cols).
// W/U pre-split to bf16 hi/lo MFMA B-fragments held in registers.
// h exchanged per step through a device-coherent staging buffer + counter barrier.

#define T_STEPS 2048
#define BATCH   64
#define DIM     256
#define HID     256
#define NWG     64
#define PKEEP   0.7f

typedef __attribute__((ext_vector_type(8))) short  s16x8;
typedef __attribute__((ext_vector_type(4))) float  f32x4;
typedef unsigned short u16;

// workspace layout (bytes from d_ws):
//   [0, 16384)            : int counters cnt[0..4095] (per-step arrival barrier)
//   [16384, 16384+4*32768): hbuf planes  (parity*2 + hi/lo) of [64][256] bf16
//   [147456, +4*32768)    : xstage planes (parity*2 + hi/lo) of [64][256] bf16
#define CNT_BYTES   16384
#define PLANE_ELEMS (BATCH * HID)      // 16384
#define PLANE_BYTES (PLANE_ELEMS * 2)  // 32768
#define HBUF_OFF    CNT_BYTES
#define XSTG_OFF    (CNT_BYTES + 4 * PLANE_BYTES)
#define ZERO_INTS   ((CNT_BYTES + 2 * PLANE_BYTES) / 4)  // cnt + hbuf parity0 hi/lo

__device__ __forceinline__ u16 f2bf(float f) {
  unsigned x = __float_as_uint(f);
  unsigned r = (x + 0x7fffu + ((x >> 16) & 1u)) >> 16;  // RNE
  return (u16)r;
}
__device__ __forceinline__ float bf2f(u16 u) { return __uint_as_float(((unsigned)u) << 16); }

__device__ __forceinline__ float sigm(float v) { return 1.0f / (1.0f + __expf(-v)); }
__device__ __forceinline__ float tanh_f(float v) {
  float e = __expf(-2.0f * fabsf(v));
  float r = (1.0f - e) / (1.0f + e);
  return v < 0.0f ? -r : r;
}

__global__ void lstm_zero_ws(int* __restrict__ p) {
  int i = blockIdx.x * 256 + threadIdx.x;
  if (i < ZERO_INTS) p[i] = 0;
}

// WSTAG encodes ws_size bracket (probe via rocprof dispatch name):
// 4: >=640MB, 3: >=320MB, 2: >=16MB, 1: >=1MB, 0: smaller
template <int WSTAG>
__global__ __launch_bounds__(256, 1) void lstm_persist(
    const float* __restrict__ x, const int* __restrict__ lens,
    const float* __restrict__ W, const float* __restrict__ U,
    const float* __restrict__ bih, const float* __restrict__ bhh,
    float* __restrict__ out, int* __restrict__ cnt,
    u16* __restrict__ hbuf, u16* __restrict__ xstg) {
  const int wg   = blockIdx.x;   // 0..63, owns h-cols [wg*4, wg*4+4)
  const int tid  = threadIdx.x;  // 0..255
  const int lane = tid & 63;
  const int wave = tid >> 6;     // M-tile index (16 batch rows each)
  const int n16  = lane & 15;    // column within 16-wide N tile
  const int kgrp = lane >> 4;    // k-group (8 consecutive k per lane)

  // ---- build persistent B fragments: 16 gate cols = rows of W/U, hi/lo split
  // col n16 -> gate (n16>>2), hcol wg*4 + (n16&3)
  const int grow = (n16 >> 2) * HID + wg * 4 + (n16 & 3);
  s16x8 BWh[8], BWl[8], BUh[8], BUl[8];
#pragma unroll
  for (int ks = 0; ks < 8; ++ks) {
    const int base = grow * DIM + ks * 32 + kgrp * 8;
    s16x8 wh, wl, uh, ul;
#pragma unroll
    for (int e = 0; e < 8; ++e) {
      float wv = W[base + e];
      u16 w1 = f2bf(wv);
      wh[e] = (short)w1;
      wl[e] = (short)f2bf(wv - bf2f(w1));
      float uv = U[base + e];
      u16 u1 = f2bf(uv);
      uh[e] = (short)u1;
      ul[e] = (short)f2bf(uv - bf2f(u1));
    }
    BWh[ks] = wh; BWl[ks] = wl; BUh[ks] = uh; BUl[ks] = ul;
  }

  // ---- cell-update thread mapping: tid -> (b, j); owns c/h in registers
  const int cb = tid >> 2;
  const int cj = tid & 3;
  const int hcol = wg * 4 + cj;
  const float bi = bih[0 * HID + hcol] + bhh[0 * HID + hcol];
  const float bfo = bih[1 * HID + hcol] + bhh[1 * HID + hcol];
  const float bg = bih[2 * HID + hcol] + bhh[2 * HID + hcol];
  const float bo = bih[3 * HID + hcol] + bhh[3 * HID + hcol];
  const int len = lens[cb];
  float hreg = 0.0f, creg = 0.0f;

  __shared__ float glds[BATCH][17];

  // ---- prologue: stage x(0)*p as bf16 hi/lo into parity 0, then arrive cnt[0]
  {
    float xv = x[wg * DIM + tid] * PKEEP;
    u16 xh = f2bf(xv);
    u16 xl = f2bf(xv - bf2f(xh));
    __hip_atomic_store(&xstg[0 * PLANE_ELEMS + wg * DIM + tid], xh, __ATOMIC_RELAXED, __HIP_MEMORY_SCOPE_AGENT);
    __hip_atomic_store(&xstg[1 * PLANE_ELEMS + wg * DIM + tid], xl, __ATOMIC_RELAXED, __HIP_MEMORY_SCOPE_AGENT);
  }
  __syncthreads();  // drains vmcnt before arrival
  if (tid == 0) __hip_atomic_fetch_add(&cnt[0], 1, __ATOMIC_RELAXED, __HIP_MEMORY_SCOPE_AGENT);

  const int arow = wave * 16 + n16;          // A row for fragment loads
  const int abase = arow * DIM + kgrp * 8;   // element offset within plane

  for (int t = 0; t < T_STEPS; ++t) {
    const int par = t & 1, npar = par ^ 1;
    // ---- barrier: wait until all WGs published h(t) and xstage(t)
    if (tid == 0) {
      while (__hip_atomic_load(&cnt[t], __ATOMIC_RELAXED, __HIP_MEMORY_SCOPE_AGENT) < NWG)
        __builtin_amdgcn_s_sleep(1);
    }
    __syncthreads();
    __builtin_amdgcn_fence(__ATOMIC_ACQUIRE, "agent");  // invalidate stale L1/L2

    // ---- A fragment loads (x and h, hi/lo)
    const u16* xhp = xstg + (par * 2 + 0) * PLANE_ELEMS;
    const u16* xlp = xstg + (par * 2 + 1) * PLANE_ELEMS;
    const u16* hhp = hbuf + (par * 2 + 0) * PLANE_ELEMS;
    const u16* hlp = hbuf + (par * 2 + 1) * PLANE_ELEMS;
    s16x8 AXh[8], AXl[8], AHh[8], AHl[8];
#pragma unroll
    for (int ks = 0; ks < 8; ++ks) {
      AXh[ks] = *(const s16x8*)(xhp + abase + ks * 32);
      AXl[ks] = *(const s16x8*)(xlp + abase + ks * 32);
      AHh[ks] = *(const s16x8*)(hhp + abase + ks * 32);
      AHl[ks] = *(const s16x8*)(hlp + abase + ks * 32);
    }
    // prefetch next x row for staging (off critical path)
    float xv = 0.0f;
    if (t + 1 < T_STEPS) xv = x[(t + 1) * BATCH * DIM + wg * DIM + tid];

    // ---- MFMA: gates tile [16 rows x 16 cols], split-bf16 (3 products per part)
    f32x4 acc = {0.0f, 0.0f, 0.0f, 0.0f};
#pragma unroll
    for (int ks = 0; ks < 8; ++ks) {
      acc = __builtin_amdgcn_mfma_f32_16x16x32_bf16(AXh[ks], BWh[ks], acc, 0, 0, 0);
      acc = __builtin_amdgcn_mfma_f32_16x16x32_bf16(AXl[ks], BWh[ks], acc, 0, 0, 0);
      acc = __builtin_amdgcn_mfma_f32_16x16x32_bf16(AXh[ks], BWl[ks], acc, 0, 0, 0);
      acc = __builtin_amdgcn_mfma_f32_16x16x32_bf16(AHh[ks], BUh[ks], acc, 0, 0, 0);
      acc = __builtin_amdgcn_mfma_f32_16x16x32_bf16(AHl[ks], BUh[ks], acc, 0, 0, 0);
      acc = __builtin_amdgcn_mfma_f32_16x16x32_bf16(AHh[ks], BUl[ks], acc, 0, 0, 0);
    }

    // ---- C frag -> LDS (D layout: col=lane&15, row=(lane>>4)*4+reg)
    const int crow = wave * 16 + kgrp * 4;
#pragma unroll
    for (int r = 0; r < 4; ++r) glds[crow + r][n16] = acc[r];
    __syncthreads();

    // ---- cell update
    float gi = glds[cb][0 + cj] + bi;
    float gf = glds[cb][4 + cj] + bfo;
    float gg = glds[cb][8 + cj] + bg;
    float go = glds[cb][12 + cj] + bo;
    float it = sigm(gi), ft = sigm(gf), ot = sigm(go);
    float gt = tanh_f(gg);
    float cnew = ft * creg + it * gt;
    float hnew = ot * tanh_f(cnew);
    const bool act = (t < len);
    out[t * BATCH * HID + cb * HID + hcol] = act ? hnew : 0.0f;
    if (act) { creg = cnew; hreg = hnew; }

    // ---- publish h(t+1)*p (hi/lo) to the other parity, device-coherent stores
    float hp = hreg * PKEEP;
    u16 hh = f2bf(hp);
    u16 hl = f2bf(hp - bf2f(hh));
    __hip_atomic_store(&hbuf[(npar * 2 + 0) * PLANE_ELEMS + cb * HID + hcol], hh, __ATOMIC_RELAXED, __HIP_MEMORY_SCOPE_AGENT);
    __hip_atomic_store(&hbuf[(npar * 2 + 1) * PLANE_ELEMS + cb * HID + hcol], hl, __ATOMIC_RELAXED, __HIP_MEMORY_SCOPE_AGENT);

    // ---- stage x(t+1)*p (hi/lo)
    if (t + 1 < T_STEPS) {
      float xs = xv * PKEEP;
      u16 xh = f2bf(xs);
      u16 xl = f2bf(xs - bf2f(xh));
      __hip_atomic_store(&xstg[(npar * 2 + 0) * PLANE_ELEMS + wg * DIM + tid], xh, __ATOMIC_RELAXED, __HIP_MEMORY_SCOPE_AGENT);
      __hip_atomic_store(&xstg[(npar * 2 + 1) * PLANE_ELEMS + wg * DIM + tid], xl, __ATOMIC_RELAXED, __HIP_MEMORY_SCOPE_AGENT);
    }

    __syncthreads();  // drains all publish stores (vmcnt(0) before s_barrier)
    if (tid == 0) __hip_atomic_fetch_add(&cnt[t + 1], 1, __ATOMIC_RELAXED, __HIP_MEMORY_SCOPE_AGENT);
  }

  // ---- epilogue: h_n, c_n
  out[T_STEPS * BATCH * HID + cb * HID + hcol] = hreg;
  out[T_STEPS * BATCH * HID + BATCH * HID + cb * HID + hcol] = creg;
}

extern "C" void kernel_launch(void* const* d_in, const int* in_sizes, int n_in,
                              void* d_out, int out_size, void* d_ws, size_t ws_size,
                              hipStream_t stream) {
  const float* x   = (const float*)d_in[0];
  const int*   len = (const int*)d_in[1];
  const float* W   = (const float*)d_in[2];
  const float* U   = (const float*)d_in[3];
  const float* bih = (const float*)d_in[4];
  const float* bhh = (const float*)d_in[5];
  float* out = (float*)d_out;
  char*  ws  = (char*)d_ws;
  int* cnt  = (int*)ws;
  u16* hbuf = (u16*)(ws + HBUF_OFF);
  u16* xstg = (u16*)(ws + XSTG_OFF);

  lstm_zero_ws<<<dim3((ZERO_INTS + 255) / 256), dim3(256), 0, stream>>>(cnt);

#define LSTM_LAUNCH(TAG)                                                        \
  lstm_persist<TAG><<<dim3(NWG), dim3(256), 0, stream>>>(x, len, W, U, bih, bhh, \
                                                         out, cnt, hbuf, xstg)
  if      (ws_size >= (size_t)640 * 1024 * 1024) LSTM_LAUNCH(4);
  else if (ws_size >= (size_t)320 * 1024 * 1024) LSTM_LAUNCH(3);
  else if (ws_size >= (size_t)16 * 1024 * 1024)  LSTM_LAUNCH(2);
  else if (ws_size >= (size_t)1 * 1024 * 1024)   LSTM_LAUNCH(1);
  else                                           LSTM_LAUNCH(0);
#undef LSTM_LAUNCH
}

// Round 2
// 16747.531 us; speedup vs baseline: 1.0263x; 1.0263x over previous
//
#include <hip/hip_runtime.h>

// LSTM persistent recurrence v2 for MI355X.
// - per-WG step flags (no counter RMW), hard spin
// - no acquire fence: h exchange read via sc0/sc1 L2-bypass asm loads only
// - x-part off the coherent path: Gx-precompute GEMM (ws>=513MB) /
//   xsplit planes (ws>=129MB) / inline fp32->bf16 convert (fallback)

#define T_STEPS 2048
#define BATCH   64
#define DIM     256
#define HID     256
#define NWG     64
#define PKEEP   0.7f
#define G4      (4 * HID)                 // 1024
#define PLANE_ELEMS (BATCH * HID)         // 16384
#define XEL     (T_STEPS * BATCH * DIM)   // 33554432

typedef __attribute__((ext_vector_type(8))) short s16x8;
typedef __attribute__((ext_vector_type(4))) short s16x4;
typedef __attribute__((ext_vector_type(4))) float f32x4;
typedef unsigned short u16;

// ws layout: [0,256) flags[64]; [4096, 4096+4*32768) h planes (par*2+{hi,lo});
// [1MB, ...) big region: Gx fp32 512MB  OR  xsplit hi/lo planes 128MB
#define HBUF_OFF  4096
#define BIG_OFF   (1 << 20)
#define ZERO_INTS ((4096 + 2 * PLANE_ELEMS * 2) / 4)  // flags+pad + parity0 hi/lo

__device__ __forceinline__ u16 f2bf_rne(float f) {
  unsigned x = __float_as_uint(f);
  return (u16)((x + 0x7fffu + ((x >> 16) & 1u)) >> 16);
}
__device__ __forceinline__ float bf2f(u16 u) { return __uint_as_float(((unsigned)u) << 16); }
__device__ __forceinline__ float sigm(float v) { return 1.0f / (1.0f + __expf(-v)); }
__device__ __forceinline__ float tanh_f(float v) {
  float e = __expf(-2.0f * fabsf(v));
  float r = (1.0f - e) / (1.0f + e);
  return v < 0.0f ? -r : r;
}

__global__ void lstm_zero_ws(int* __restrict__ p) {
  int i = blockIdx.x * 256 + threadIdx.x;
  if (i < ZERO_INTS) p[i] = 0;
}

// ---------- Gx = (x*p) @ W^T one-shot GEMM (fp32-accurate via split-bf16) ----------
__global__ __launch_bounds__(256, 1) void lstm_gx_gemm(
    const float* __restrict__ x, const float* __restrict__ W, float* __restrict__ Gx) {
  const int nsl = blockIdx.x & 15;   // 64-col N slice
  const int mch = blockIdx.x >> 4;   // 8192-row M chunk
  const int n0 = nsl * 64;
  const int tid = threadIdx.x, lane = tid & 63, wave = tid >> 6;
  const int n16 = lane & 15, kgrp = lane >> 4;

  __shared__ u16 Bh[64 * 256], Bl[64 * 256];  // XOR-swizzled (T2) hi/lo W planes
  for (int i = tid; i < 64 * 256; i += 256) {
    int col = i >> 8, k = i & 255;
    float wv = W[(n0 + col) * 256 + k];
    unsigned hb = __float_as_uint(wv) & 0xFFFF0000u;
    int off = (col * 512 + k * 2) ^ ((col & 7) << 4);
    *(u16*)((char*)Bh + off) = (u16)(hb >> 16);
    *(u16*)((char*)Bl + off) = f2bf_rne(wv - __uint_as_float(hb));
  }
  __syncthreads();

  for (int it = 0; it < 128; ++it) {
    const long r = (long)mch * 8192 + it * 64 + wave * 16 + n16;
    const float* xr = x + r * DIM + kgrp * 8;
    s16x8 Ah[8], Al[8];
#pragma unroll
    for (int ks = 0; ks < 8; ++ks) {
      f32x4 a = *(const f32x4*)(xr + ks * 32);
      f32x4 b = *(const f32x4*)(xr + ks * 32 + 4);
#pragma unroll
      for (int e = 0; e < 8; ++e) {
        float v = (e < 4 ? a[e] : b[e - 4]) * PKEEP;
        unsigned hb = __float_as_uint(v) & 0xFFFF0000u;
        Ah[ks][e] = (short)(hb >> 16);
        Al[ks][e] = (short)(u16)(__float_as_uint(v - __uint_as_float(hb)) >> 16);
      }
    }
#pragma unroll
    for (int nt = 0; nt < 4; ++nt) {
      f32x4 acc = {0.f, 0.f, 0.f, 0.f};
      const int col = nt * 16 + n16;
      const int sw = (col & 7) << 4;
#pragma unroll
      for (int ks = 0; ks < 8; ++ks) {
        const int off = (col * 512 + (ks * 32 + kgrp * 8) * 2) ^ sw;
        s16x8 bh = *(const s16x8*)((const char*)Bh + off);
        s16x8 bl = *(const s16x8*)((const char*)Bl + off);
        acc = __builtin_amdgcn_mfma_f32_16x16x32_bf16(Ah[ks], bh, acc, 0, 0, 0);
        acc = __builtin_amdgcn_mfma_f32_16x16x32_bf16(Al[ks], bh, acc, 0, 0, 0);
        acc = __builtin_amdgcn_mfma_f32_16x16x32_bf16(Ah[ks], bl, acc, 0, 0, 0);
      }
      const long mrow = (long)mch * 8192 + it * 64 + wave * 16 + kgrp * 4;
#pragma unroll
      for (int rr = 0; rr < 4; ++rr)
        Gx[(mrow + rr) * G4 + n0 + col] = acc[rr];
    }
  }
}

// ---------- x -> bf16 hi/lo planes (xsplit mode prologue) ----------
__global__ void lstm_xsplit_prep(const float* __restrict__ x,
                                 u16* __restrict__ xh, u16* __restrict__ xl) {
  long i = ((long)blockIdx.x * 256 + threadIdx.x) * 4;
  if (i >= (long)XEL) return;
  f32x4 v = *(const f32x4*)(x + i);
  s16x4 h, l;
#pragma unroll
  for (int e = 0; e < 4; ++e) {
    float val = v[e] * PKEEP;
    unsigned hb = __float_as_uint(val) & 0xFFFF0000u;
    h[e] = (short)(hb >> 16);
    l[e] = (short)(u16)(__float_as_uint(val - __uint_as_float(hb)) >> 16);
  }
  *(s16x4*)(xh + i) = h;
  *(s16x4*)(xl + i) = l;
}

// ---------- persistent recurrence ----------
// MODE: 0 = Gx precomputed, 1 = xsplit planes, 2 = direct fp32 convert
template <int MODE>
__device__ __forceinline__ void recur_body(
    const float* __restrict__ x, const int* __restrict__ lens,
    const float* __restrict__ W, const float* __restrict__ U,
    const float* __restrict__ bih, const float* __restrict__ bhh,
    float* __restrict__ out, int* __restrict__ flags, u16* __restrict__ hbuf,
    const float* __restrict__ Gx, const u16* __restrict__ xsph, const u16* __restrict__ xspl) {
  const int wg = blockIdx.x, tid = threadIdx.x;
  const int lane = tid & 63, wave = tid >> 6;
  const int n16 = lane & 15, kgrp = lane >> 4;

  // persistent B fragments (RNE hi/lo split): col n16 -> gate n16>>2, hcol wg*4+(n16&3)
  const int grow = (n16 >> 2) * HID + wg * 4 + (n16 & 3);
  s16x8 BUh[8], BUl[8], BWh[8], BWl[8];
#pragma unroll
  for (int ks = 0; ks < 8; ++ks) {
    const int base = grow * DIM + ks * 32 + kgrp * 8;
#pragma unroll
    for (int e = 0; e < 8; ++e) {
      float uv = U[base + e];
      u16 uh = f2bf_rne(uv);
      BUh[ks][e] = (short)uh;
      BUl[ks][e] = (short)f2bf_rne(uv - bf2f(uh));
      if constexpr (MODE != 0) {
        float wv = W[base + e];
        u16 wh = f2bf_rne(wv);
        BWh[ks][e] = (short)wh;
        BWl[ks][e] = (short)f2bf_rne(wv - bf2f(wh));
      }
    }
  }

  const int cb = tid >> 2, cj = tid & 3;
  const int hcol = wg * 4 + cj;
  const float bi  = bih[0 * HID + hcol] + bhh[0 * HID + hcol];
  const float bfo = bih[1 * HID + hcol] + bhh[1 * HID + hcol];
  const float bg  = bih[2 * HID + hcol] + bhh[2 * HID + hcol];
  const float bo  = bih[3 * HID + hcol] + bhh[3 * HID + hcol];
  const int len = lens[cb];
  float hreg = 0.0f, creg = 0.0f;

  const int arow = wave * 16 + n16;
  const int abase = arow * DIM + kgrp * 8;

  __shared__ float glds[BATCH][17];

  for (int t = 0; t < T_STEPS; ++t) {
    const int par = t & 1, npar = par ^ 1;

    // ---- prefetch x-part for THIS step (read-only data, cached, overlaps poll)
    float gx0 = 0.f, gx1 = 0.f, gx2 = 0.f, gx3 = 0.f;
    s16x8 AXh[8], AXl[8];
    f32x4 xfa[8], xfb[8];
    if constexpr (MODE == 0) {
      const float* g = Gx + (long)t * (BATCH * G4) + cb * G4 + hcol;
      gx0 = g[0]; gx1 = g[HID]; gx2 = g[2 * HID]; gx3 = g[3 * HID];
    } else if constexpr (MODE == 1) {
      const u16* ph = xsph + (long)t * (BATCH * DIM) + abase;
      const u16* pl = xspl + (long)t * (BATCH * DIM) + abase;
#pragma unroll
      for (int ks = 0; ks < 8; ++ks) {
        AXh[ks] = *(const s16x8*)(ph + ks * 32);
        AXl[ks] = *(const s16x8*)(pl + ks * 32);
      }
    } else {
      const float* xr = x + (long)t * (BATCH * DIM) + abase;
#pragma unroll
      for (int ks = 0; ks < 8; ++ks) {
        xfa[ks] = *(const f32x4*)(xr + ks * 32);
        xfb[ks] = *(const f32x4*)(xr + ks * 32 + 4);
      }
    }

    // ---- wait for all WGs to have published h(t) (step-tagged flags, hard spin)
    if (t > 0) {
      int fv;
      do {
        fv = __hip_atomic_load(&flags[lane], __ATOMIC_RELAXED, __HIP_MEMORY_SCOPE_AGENT);
      } while (__any(fv < t));
    }

    // ---- h fragments via L2-bypass loads (only coherent traffic in the loop)
    s16x8 AHh[8], AHl[8];
    {
      const u16* hh = hbuf + (par * 2 + 0) * PLANE_ELEMS + abase;
      const u16* hl = hbuf + (par * 2 + 1) * PLANE_ELEMS + abase;
#pragma unroll
      for (int ks = 0; ks < 8; ++ks) {
        asm volatile("global_load_dwordx4 %0, %1, off sc0 sc1"
                     : "=v"(AHh[ks]) : "v"(hh + ks * 32) : "memory");
        asm volatile("global_load_dwordx4 %0, %1, off sc0 sc1"
                     : "=v"(AHl[ks]) : "v"(hl + ks * 32) : "memory");
      }
    }

    // ---- DIRECT: convert x under the h-load latency
    if constexpr (MODE == 2) {
#pragma unroll
      for (int ks = 0; ks < 8; ++ks) {
#pragma unroll
        for (int e = 0; e < 8; ++e) {
          float v = (e < 4 ? xfa[ks][e] : xfb[ks][e - 4]) * PKEEP;
          unsigned hb = __float_as_uint(v) & 0xFFFF0000u;
          AXh[ks][e] = (short)(hb >> 16);
          AXl[ks][e] = (short)(u16)(__float_as_uint(v - __uint_as_float(hb)) >> 16);
        }
      }
    }

    asm volatile("s_waitcnt vmcnt(0)" ::: "memory");
    __builtin_amdgcn_sched_barrier(0);

    // ---- gate GEMM tile [16x16], split-bf16
    f32x4 acc = {0.f, 0.f, 0.f, 0.f};
#pragma unroll
    for (int ks = 0; ks < 8; ++ks) {
      acc = __builtin_amdgcn_mfma_f32_16x16x32_bf16(AHh[ks], BUh[ks], acc, 0, 0, 0);
      acc = __builtin_amdgcn_mfma_f32_16x16x32_bf16(AHl[ks], BUh[ks], acc, 0, 0, 0);
      acc = __builtin_amdgcn_mfma_f32_16x16x32_bf16(AHh[ks], BUl[ks], acc, 0, 0, 0);
      if constexpr (MODE != 0) {
        acc = __builtin_amdgcn_mfma_f32_16x16x32_bf16(AXh[ks], BWh[ks], acc, 0, 0, 0);
        acc = __builtin_amdgcn_mfma_f32_16x16x32_bf16(AXl[ks], BWh[ks], acc, 0, 0, 0);
        acc = __builtin_amdgcn_mfma_f32_16x16x32_bf16(AXh[ks], BWl[ks], acc, 0, 0, 0);
      }
    }

    // ---- C frag -> LDS (col=lane&15, row=(lane>>4)*4+reg)
    const int crow = wave * 16 + kgrp * 4;
#pragma unroll
    for (int r = 0; r < 4; ++r) glds[crow + r][n16] = acc[r];
    __syncthreads();

    // ---- cell update
    float gi = glds[cb][0 + cj]  + bi;
    float gf = glds[cb][4 + cj]  + bfo;
    float gg = glds[cb][8 + cj]  + bg;
    float go = glds[cb][12 + cj] + bo;
    if constexpr (MODE == 0) { gi += gx0; gf += gx1; gg += gx2; go += gx3; }
    float it = sigm(gi), ft = sigm(gf), ot = sigm(go);
    float gt = tanh_f(gg);
    float cnew = ft * creg + it * gt;
    float hnew = ot * tanh_f(cnew);
    const bool act = (t < len);
    out[(long)t * (BATCH * HID) + cb * HID + hcol] = act ? hnew : 0.0f;
    if (act) { creg = cnew; hreg = hnew; }

    // ---- publish h(t+1)*p (hi trunc + lo RNE), agent-coherent stores
    float hp = hreg * PKEEP;
    unsigned hb = __float_as_uint(hp) & 0xFFFF0000u;
    u16 hh = (u16)(hb >> 16);
    u16 hl = f2bf_rne(hp - __uint_as_float(hb));
    __hip_atomic_store(&hbuf[(npar * 2 + 0) * PLANE_ELEMS + cb * HID + hcol], hh,
                       __ATOMIC_RELAXED, __HIP_MEMORY_SCOPE_AGENT);
    __hip_atomic_store(&hbuf[(npar * 2 + 1) * PLANE_ELEMS + cb * HID + hcol], hl,
                       __ATOMIC_RELAXED, __HIP_MEMORY_SCOPE_AGENT);

    __syncthreads();  // drains all waves' publish stores before flag
    if (tid == 0)
      __hip_atomic_store(&flags[wg], t + 1, __ATOMIC_RELEASE, __HIP_MEMORY_SCOPE_AGENT);
  }

  out[(long)T_STEPS * (BATCH * HID) + cb * HID + hcol] = hreg;
  out[(long)T_STEPS * (BATCH * HID) + BATCH * HID + cb * HID + hcol] = creg;
}

#define RECUR_PARAMS                                                          \
  const float* __restrict__ x, const int* __restrict__ lens,                  \
  const float* __restrict__ W, const float* __restrict__ U,                   \
  const float* __restrict__ bih, const float* __restrict__ bhh,               \
  float* __restrict__ out, int* __restrict__ flags, u16* __restrict__ hbuf,   \
  const float* __restrict__ Gx, const u16* __restrict__ xsph,                 \
  const u16* __restrict__ xspl
#define RECUR_ARGS x, lens, W, U, bih, bhh, out, flags, hbuf, Gx, xsph, xspl

__global__ __launch_bounds__(256, 1) void lstm_recur_gx(RECUR_PARAMS)     { recur_body<0>(RECUR_ARGS); }
__global__ __launch_bounds__(256, 1) void lstm_recur_xsplit(RECUR_PARAMS) { recur_body<1>(RECUR_ARGS); }
__global__ __launch_bounds__(256, 1) void lstm_recur_direct(RECUR_PARAMS) { recur_body<2>(RECUR_ARGS); }

extern "C" void kernel_launch(void* const* d_in, const int* in_sizes, int n_in,
                              void* d_out, int out_size, void* d_ws, size_t ws_size,
                              hipStream_t stream) {
  const float* x   = (const float*)d_in[0];
  const int*   len = (const int*)d_in[1];
  const float* W   = (const float*)d_in[2];
  const float* U   = (const float*)d_in[3];
  const float* bih = (const float*)d_in[4];
  const float* bhh = (const float*)d_in[5];
  float* out = (float*)d_out;
  char*  ws  = (char*)d_ws;
  int* flags = (int*)ws;
  u16* hbuf  = (u16*)(ws + HBUF_OFF);
  char* big  = ws + BIG_OFF;

  lstm_zero_ws<<<dim3((ZERO_INTS + 255) / 256), dim3(256), 0, stream>>>((int*)ws);

  const size_t need_gx = (size_t)BIG_OFF + (size_t)T_STEPS * BATCH * G4 * 4;  // ~513MB
  const size_t need_xs = (size_t)BIG_OFF + (size_t)XEL * 2 * 2;               // ~129MB
  if (ws_size >= need_gx) {
    float* Gx = (float*)big;
    lstm_gx_gemm<<<dim3(256), dim3(256), 0, stream>>>(x, W, Gx);
    lstm_recur_gx<<<dim3(NWG), dim3(256), 0, stream>>>(x, len, W, U, bih, bhh, out,
                                                       flags, hbuf, Gx, nullptr, nullptr);
  } else if (ws_size >= need_xs) {
    u16* xh = (u16*)big;
    u16* xl = xh + (long)XEL;
    lstm_xsplit_prep<<<dim3(32768), dim3(256), 0, stream>>>(x, xh, xl);
    lstm_recur_xsplit<<<dim3(NWG), dim3(256), 0, stream>>>(x, len, W, U, bih, bhh, out,
                                                           flags, hbuf, nullptr, xh, xl);
  } else {
    lstm_recur_direct<<<dim3(NWG), dim3(256), 0, stream>>>(x, len, W, U, bih, bhh, out,
                                                           flags, hbuf, nullptr, nullptr, nullptr);
  }
}

// Round 3
// 10833.723 us; speedup vs baseline: 1.5866x; 1.5459x over previous
//
#include <hip/hip_runtime.h>

// LSTM persistent recurrence v3 for MI355X.
// v2 -> v3: ALL cross-WG protocol traffic (flag poll loads, flag stores,
// h publish stores) now uses explicit sc0 sc1 inline-asm ops so no XCD-L2
// stale line can delay discovery (per-XCD L2s have no invalidation).
// Modes unchanged: Gx GEMM (ws>=513MB) / xsplit planes (ws>=129MB) / direct.

#define T_STEPS 2048
#define BATCH   64
#define DIM     256
#define HID     256
#define NWG     64
#define PKEEP   0.7f
#define G4      (4 * HID)                 // 1024
#define PLANE_ELEMS (BATCH * HID)         // 16384
#define XEL     (T_STEPS * BATCH * DIM)   // 33554432

typedef __attribute__((ext_vector_type(8))) short s16x8;
typedef __attribute__((ext_vector_type(4))) short s16x4;
typedef __attribute__((ext_vector_type(4))) float f32x4;
typedef unsigned short u16;

// ws layout: [0,256) flags[64]; [4096, 4096+4*32768) h planes (par*2+{hi,lo});
// [1MB, ...) big region: Gx fp32 512MB  OR  xsplit hi/lo planes 128MB
#define HBUF_OFF  4096
#define BIG_OFF   (1 << 20)
#define ZERO_INTS ((4096 + 2 * PLANE_ELEMS * 2) / 4)  // flags+pad + parity0 hi/lo

__device__ __forceinline__ u16 f2bf_rne(float f) {
  unsigned x = __float_as_uint(f);
  return (u16)((x + 0x7fffu + ((x >> 16) & 1u)) >> 16);
}
__device__ __forceinline__ float bf2f(u16 u) { return __uint_as_float(((unsigned)u) << 16); }
__device__ __forceinline__ float sigm(float v) { return 1.0f / (1.0f + __expf(-v)); }
__device__ __forceinline__ float tanh_f(float v) {
  float e = __expf(-2.0f * fabsf(v));
  float r = (1.0f - e) / (1.0f + e);
  return v < 0.0f ? -r : r;
}

// coherent (coherence-point) memory ops: never served by a stale XCD L2 line
__device__ __forceinline__ int coh_load_i32(const int* p) {
  int v;
  asm volatile("global_load_dword %0, %1, off sc0 sc1\n\ts_waitcnt vmcnt(0)"
               : "=v"(v) : "v"(p) : "memory");
  return v;
}
__device__ __forceinline__ void coh_store_i32(int* p, int v) {
  asm volatile("global_store_dword %0, %1, off sc0 sc1" :: "v"(p), "v"(v) : "memory");
}
__device__ __forceinline__ void coh_store_u16(u16* p, unsigned v) {
  asm volatile("global_store_short %0, %1, off sc0 sc1" :: "v"(p), "v"(v) : "memory");
}

__global__ void lstm_zero_ws(int* __restrict__ p) {
  int i = blockIdx.x * 256 + threadIdx.x;
  if (i < ZERO_INTS) p[i] = 0;
}

// ---------- Gx = (x*p) @ W^T one-shot GEMM (fp32-accurate via split-bf16) ----------
__global__ __launch_bounds__(256, 1) void lstm_gx_gemm(
    const float* __restrict__ x, const float* __restrict__ W, float* __restrict__ Gx) {
  const int nsl = blockIdx.x & 15;
  const int mch = blockIdx.x >> 4;
  const int n0 = nsl * 64;
  const int tid = threadIdx.x, lane = tid & 63, wave = tid >> 6;
  const int n16 = lane & 15, kgrp = lane >> 4;

  __shared__ u16 Bh[64 * 256], Bl[64 * 256];
  for (int i = tid; i < 64 * 256; i += 256) {
    int col = i >> 8, k = i & 255;
    float wv = W[(n0 + col) * 256 + k];
    unsigned hb = __float_as_uint(wv) & 0xFFFF0000u;
    int off = (col * 512 + k * 2) ^ ((col & 7) << 4);
    *(u16*)((char*)Bh + off) = (u16)(hb >> 16);
    *(u16*)((char*)Bl + off) = f2bf_rne(wv - __uint_as_float(hb));
  }
  __syncthreads();

  for (int it = 0; it < 128; ++it) {
    const long r = (long)mch * 8192 + it * 64 + wave * 16 + n16;
    const float* xr = x + r * DIM + kgrp * 8;
    s16x8 Ah[8], Al[8];
#pragma unroll
    for (int ks = 0; ks < 8; ++ks) {
      f32x4 a = *(const f32x4*)(xr + ks * 32);
      f32x4 b = *(const f32x4*)(xr + ks * 32 + 4);
#pragma unroll
      for (int e = 0; e < 8; ++e) {
        float v = (e < 4 ? a[e] : b[e - 4]) * PKEEP;
        unsigned hb = __float_as_uint(v) & 0xFFFF0000u;
        Ah[ks][e] = (short)(hb >> 16);
        Al[ks][e] = (short)(u16)(__float_as_uint(v - __uint_as_float(hb)) >> 16);
      }
    }
#pragma unroll
    for (int nt = 0; nt < 4; ++nt) {
      f32x4 acc = {0.f, 0.f, 0.f, 0.f};
      const int col = nt * 16 + n16;
      const int sw = (col & 7) << 4;
#pragma unroll
      for (int ks = 0; ks < 8; ++ks) {
        const int off = (col * 512 + (ks * 32 + kgrp * 8) * 2) ^ sw;
        s16x8 bh = *(const s16x8*)((const char*)Bh + off);
        s16x8 bl = *(const s16x8*)((const char*)Bl + off);
        acc = __builtin_amdgcn_mfma_f32_16x16x32_bf16(Ah[ks], bh, acc, 0, 0, 0);
        acc = __builtin_amdgcn_mfma_f32_16x16x32_bf16(Al[ks], bh, acc, 0, 0, 0);
        acc = __builtin_amdgcn_mfma_f32_16x16x32_bf16(Ah[ks], bl, acc, 0, 0, 0);
      }
      const long mrow = (long)mch * 8192 + it * 64 + wave * 16 + kgrp * 4;
#pragma unroll
      for (int rr = 0; rr < 4; ++rr)
        Gx[(mrow + rr) * G4 + n0 + col] = acc[rr];
    }
  }
}

// ---------- x -> bf16 hi/lo planes (xsplit mode prologue) ----------
__global__ void lstm_xsplit_prep(const float* __restrict__ x,
                                 u16* __restrict__ xh, u16* __restrict__ xl) {
  long i = ((long)blockIdx.x * 256 + threadIdx.x) * 4;
  if (i >= (long)XEL) return;
  f32x4 v = *(const f32x4*)(x + i);
  s16x4 h, l;
#pragma unroll
  for (int e = 0; e < 4; ++e) {
    float val = v[e] * PKEEP;
    unsigned hb = __float_as_uint(val) & 0xFFFF0000u;
    h[e] = (short)(hb >> 16);
    l[e] = (short)(u16)(__float_as_uint(val - __uint_as_float(hb)) >> 16);
  }
  *(s16x4*)(xh + i) = h;
  *(s16x4*)(xl + i) = l;
}

// ---------- persistent recurrence ----------
// MODE: 0 = Gx precomputed, 1 = xsplit planes, 2 = direct fp32 convert
template <int MODE>
__device__ __forceinline__ void recur_body(
    const float* __restrict__ x, const int* __restrict__ lens,
    const float* __restrict__ W, const float* __restrict__ U,
    const float* __restrict__ bih, const float* __restrict__ bhh,
    float* __restrict__ out, int* __restrict__ flags, u16* __restrict__ hbuf,
    const float* __restrict__ Gx, const u16* __restrict__ xsph, const u16* __restrict__ xspl) {
  const int wg = blockIdx.x, tid = threadIdx.x;
  const int lane = tid & 63, wave = tid >> 6;
  const int n16 = lane & 15, kgrp = lane >> 4;

  // persistent B fragments: col n16 -> gate n16>>2, hcol wg*4+(n16&3)
  const int grow = (n16 >> 2) * HID + wg * 4 + (n16 & 3);
  s16x8 BUh[8], BUl[8], BWh[8], BWl[8];
#pragma unroll
  for (int ks = 0; ks < 8; ++ks) {
    const int base = grow * DIM + ks * 32 + kgrp * 8;
#pragma unroll
    for (int e = 0; e < 8; ++e) {
      float uv = U[base + e];
      u16 uh = f2bf_rne(uv);
      BUh[ks][e] = (short)uh;
      BUl[ks][e] = (short)f2bf_rne(uv - bf2f(uh));
      if constexpr (MODE != 0) {
        float wv = W[base + e];
        u16 wh = f2bf_rne(wv);
        BWh[ks][e] = (short)wh;
        BWl[ks][e] = (short)f2bf_rne(wv - bf2f(wh));
      }
    }
  }

  const int cb = tid >> 2, cj = tid & 3;
  const int hcol = wg * 4 + cj;
  const float bi  = bih[0 * HID + hcol] + bhh[0 * HID + hcol];
  const float bfo = bih[1 * HID + hcol] + bhh[1 * HID + hcol];
  const float bg  = bih[2 * HID + hcol] + bhh[2 * HID + hcol];
  const float bo  = bih[3 * HID + hcol] + bhh[3 * HID + hcol];
  const int len = lens[cb];
  float hreg = 0.0f, creg = 0.0f;

  const int arow = wave * 16 + n16;
  const int abase = arow * DIM + kgrp * 8;

  __shared__ float glds[BATCH][17];

  for (int t = 0; t < T_STEPS; ++t) {
    const int par = t & 1, npar = par ^ 1;

    // ---- prefetch x-part for THIS step (read-only, cached, overlaps poll)
    float gx0 = 0.f, gx1 = 0.f, gx2 = 0.f, gx3 = 0.f;
    s16x8 AXh[8], AXl[8];
    f32x4 xfa[8], xfb[8];
    if constexpr (MODE == 0) {
      const float* g = Gx + (long)t * (BATCH * G4) + cb * G4 + hcol;
      gx0 = g[0]; gx1 = g[HID]; gx2 = g[2 * HID]; gx3 = g[3 * HID];
    } else if constexpr (MODE == 1) {
      const u16* ph = xsph + (long)t * (BATCH * DIM) + abase;
      const u16* pl = xspl + (long)t * (BATCH * DIM) + abase;
#pragma unroll
      for (int ks = 0; ks < 8; ++ks) {
        AXh[ks] = *(const s16x8*)(ph + ks * 32);
        AXl[ks] = *(const s16x8*)(pl + ks * 32);
      }
    } else {
      const float* xr = x + (long)t * (BATCH * DIM) + abase;
#pragma unroll
      for (int ks = 0; ks < 8; ++ks) {
        xfa[ks] = *(const f32x4*)(xr + ks * 32);
        xfb[ks] = *(const f32x4*)(xr + ks * 32 + 4);
      }
    }

    // ---- wait for all WGs' h(t) publish; coherent poll loads (never stale)
    if (t > 0) {
      const int* fp = flags + lane;
      for (;;) {
        int fv = coh_load_i32(fp);
        if (!__any(fv < t)) break;
        __builtin_amdgcn_s_sleep(1);
      }
    }

    // ---- h fragments via coherent loads
    s16x8 AHh[8], AHl[8];
    {
      const u16* hh = hbuf + (par * 2 + 0) * PLANE_ELEMS + abase;
      const u16* hl = hbuf + (par * 2 + 1) * PLANE_ELEMS + abase;
#pragma unroll
      for (int ks = 0; ks < 8; ++ks) {
        asm volatile("global_load_dwordx4 %0, %1, off sc0 sc1"
                     : "=v"(AHh[ks]) : "v"(hh + ks * 32) : "memory");
        asm volatile("global_load_dwordx4 %0, %1, off sc0 sc1"
                     : "=v"(AHl[ks]) : "v"(hl + ks * 32) : "memory");
      }
    }

    // ---- DIRECT: convert x under the h-load latency
    if constexpr (MODE == 2) {
#pragma unroll
      for (int ks = 0; ks < 8; ++ks) {
#pragma unroll
        for (int e = 0; e < 8; ++e) {
          float v = (e < 4 ? xfa[ks][e] : xfb[ks][e - 4]) * PKEEP;
          unsigned hb = __float_as_uint(v) & 0xFFFF0000u;
          AXh[ks][e] = (short)(hb >> 16);
          AXl[ks][e] = (short)(u16)(__float_as_uint(v - __uint_as_float(hb)) >> 16);
        }
      }
    }

    asm volatile("s_waitcnt vmcnt(0)" ::: "memory");
    __builtin_amdgcn_sched_barrier(0);

    // ---- gate GEMM tile [16x16], split-bf16
    f32x4 acc = {0.f, 0.f, 0.f, 0.f};
#pragma unroll
    for (int ks = 0; ks < 8; ++ks) {
      acc = __builtin_amdgcn_mfma_f32_16x16x32_bf16(AHh[ks], BUh[ks], acc, 0, 0, 0);
      acc = __builtin_amdgcn_mfma_f32_16x16x32_bf16(AHl[ks], BUh[ks], acc, 0, 0, 0);
      acc = __builtin_amdgcn_mfma_f32_16x16x32_bf16(AHh[ks], BUl[ks], acc, 0, 0, 0);
      if constexpr (MODE != 0) {
        acc = __builtin_amdgcn_mfma_f32_16x16x32_bf16(AXh[ks], BWh[ks], acc, 0, 0, 0);
        acc = __builtin_amdgcn_mfma_f32_16x16x32_bf16(AXl[ks], BWh[ks], acc, 0, 0, 0);
        acc = __builtin_amdgcn_mfma_f32_16x16x32_bf16(AXh[ks], BWl[ks], acc, 0, 0, 0);
      }
    }

    // ---- C frag -> LDS (col=lane&15, row=(lane>>4)*4+reg)
    const int crow = wave * 16 + kgrp * 4;
#pragma unroll
    for (int r = 0; r < 4; ++r) glds[crow + r][n16] = acc[r];
    __syncthreads();

    // ---- cell update
    float gi = glds[cb][0 + cj]  + bi;
    float gf = glds[cb][4 + cj]  + bfo;
    float gg = glds[cb][8 + cj]  + bg;
    float go = glds[cb][12 + cj] + bo;
    if constexpr (MODE == 0) { gi += gx0; gf += gx1; gg += gx2; go += gx3; }
    float it = sigm(gi), ft = sigm(gf), ot = sigm(go);
    float gt = tanh_f(gg);
    float cnew = ft * creg + it * gt;
    float hnew = ot * tanh_f(cnew);
    const bool act = (t < len);
    if (act) { creg = cnew; hreg = hnew; }

    // ---- publish h(t+1)*p FIRST (coherent short stores), flag after drain
    float hp = hreg * PKEEP;
    unsigned hb = __float_as_uint(hp) & 0xFFFF0000u;
    unsigned hh = hb >> 16;
    unsigned hl = (unsigned)f2bf_rne(hp - __uint_as_float(hb));
    coh_store_u16(&hbuf[(npar * 2 + 0) * PLANE_ELEMS + cb * HID + hcol], hh);
    coh_store_u16(&hbuf[(npar * 2 + 1) * PLANE_ELEMS + cb * HID + hcol], hl);

    asm volatile("s_waitcnt vmcnt(0)" ::: "memory");
    __syncthreads();  // all waves' publish stores are at the coherence point
    if (tid == 0) coh_store_i32(&flags[wg], t + 1);

    // ---- out store after the flag is on its way (off other WGs' critical path)
    out[(long)t * (BATCH * HID) + cb * HID + hcol] = act ? hnew : 0.0f;
  }

  out[(long)T_STEPS * (BATCH * HID) + cb * HID + hcol] = hreg;
  out[(long)T_STEPS * (BATCH * HID) + BATCH * HID + cb * HID + hcol] = creg;
}

#define RECUR_PARAMS                                                          \
  const float* __restrict__ x, const int* __restrict__ lens,                  \
  const float* __restrict__ W, const float* __restrict__ U,                   \
  const float* __restrict__ bih, const float* __restrict__ bhh,               \
  float* __restrict__ out, int* __restrict__ flags, u16* __restrict__ hbuf,   \
  const float* __restrict__ Gx, const u16* __restrict__ xsph,                 \
  const u16* __restrict__ xspl
#define RECUR_ARGS x, lens, W, U, bih, bhh, out, flags, hbuf, Gx, xsph, xspl

__global__ __launch_bounds__(256, 1) void lstm_recur_gx(RECUR_PARAMS)     { recur_body<0>(RECUR_ARGS); }
__global__ __launch_bounds__(256, 1) void lstm_recur_xsplit(RECUR_PARAMS) { recur_body<1>(RECUR_ARGS); }
__global__ __launch_bounds__(256, 1) void lstm_recur_direct(RECUR_PARAMS) { recur_body<2>(RECUR_ARGS); }

extern "C" void kernel_launch(void* const* d_in, const int* in_sizes, int n_in,
                              void* d_out, int out_size, void* d_ws, size_t ws_size,
                              hipStream_t stream) {
  const float* x   = (const float*)d_in[0];
  const int*   len = (const int*)d_in[1];
  const float* W   = (const float*)d_in[2];
  const float* U   = (const float*)d_in[3];
  const float* bih = (const float*)d_in[4];
  const float* bhh = (const float*)d_in[5];
  float* out = (float*)d_out;
  char*  ws  = (char*)d_ws;
  int* flags = (int*)ws;
  u16* hbuf  = (u16*)(ws + HBUF_OFF);
  char* big  = ws + BIG_OFF;

  lstm_zero_ws<<<dim3((ZERO_INTS + 255) / 256), dim3(256), 0, stream>>>((int*)ws);

  const size_t need_gx = (size_t)BIG_OFF + (size_t)T_STEPS * BATCH * G4 * 4;  // ~513MB
  const size_t need_xs = (size_t)BIG_OFF + (size_t)XEL * 2 * 2;               // ~129MB
  if (ws_size >= need_gx) {
    float* Gx = (float*)big;
    lstm_gx_gemm<<<dim3(256), dim3(256), 0, stream>>>(x, W, Gx);
    lstm_recur_gx<<<dim3(NWG), dim3(256), 0, stream>>>(x, len, W, U, bih, bhh, out,
                                                       flags, hbuf, Gx, nullptr, nullptr);
  } else if (ws_size >= need_xs) {
    u16* xh = (u16*)big;
    u16* xl = xh + (long)XEL;
    lstm_xsplit_prep<<<dim3(32768), dim3(256), 0, stream>>>(x, xh, xl);
    lstm_recur_xsplit<<<dim3(NWG), dim3(256), 0, stream>>>(x, len, W, U, bih, bhh, out,
                                                           flags, hbuf, nullptr, xh, xl);
  } else {
    lstm_recur_direct<<<dim3(NWG), dim3(256), 0, stream>>>(x, len, W, U, bih, bhh, out,
                                                           flags, hbuf, nullptr, nullptr, nullptr);
  }
}

// Round 5
// 9572.881 us; speedup vs baseline: 1.7955x; 1.1317x over previous
//
#include <hip/hip_runtime.h>

// LSTM persistent recurrence v5 for MI355X.
// Device-scope (sc0 sc1) protocol only — no placement assumptions, no election.
// Tag-in-data: h published as one atomic dwordx2 (packed bf16 hi|lo, step tag);
// consumers poll the data lines directly (tag==t => data fresh, same-line
// snapshot). WG(m,n) owns rows 16m..+15 x hcols 16n..+15; the 4 row-groups are
// independent (batch rows don't couple). h staged once per WG through
// XOR-swizzled LDS. Modes: xpack planes (ws>=130MB) / direct fp32.

#define T_STEPS 2048
#define BATCH   64
#define DIM     256
#define HID     256
#define PKEEP   0.7f
#define NG      4                        // row groups
#define RPG     16                       // rows per group
#define REGION_U32 (RPG * HID * 2)       // 8192 u32 (pairs)
#define PLANE_U32  (NG * REGION_U32)     // 32768 u32 (128KB)
#define XEL     (T_STEPS * BATCH * DIM)  // 33554432

typedef __attribute__((ext_vector_type(8))) short s16x8;
typedef __attribute__((ext_vector_type(4))) float f32x4;
typedef __attribute__((ext_vector_type(4))) unsigned int u32x4;
typedef __attribute__((ext_vector_type(2))) unsigned int u32x2;
typedef unsigned int u32;
typedef unsigned short u16;

// ws layout: [4096, 4096+256KB) h pair planes [2][4][16][256][2]u32; [1MB,..) xpk
#define HBUF_OFF 4096
#define BIG_OFF  (1 << 20)
#define ZERO_INTS (2 * PLANE_U32)        // 65536

#define HISEL 0x07060302u
#define LOSEL 0x05040100u

__device__ __forceinline__ u16 f2bf_rne(float f) {
  unsigned x = __float_as_uint(f);
  return (u16)((x + 0x7fffu + ((x >> 16) & 1u)) >> 16);
}
__device__ __forceinline__ float bf2f(u16 u) { return __uint_as_float(((unsigned)u) << 16); }
__device__ __forceinline__ float sigm(float v) { return 1.0f / (1.0f + __expf(-v)); }
__device__ __forceinline__ float tanh_f(float v) {
  float e = __expf(-2.0f * fabsf(v));
  float r = (1.0f - e) / (1.0f + e);
  return v < 0.0f ? -r : r;
}
__device__ __forceinline__ u32 packbf(float v) {
  u32 uh = __float_as_uint(v) & 0xFFFF0000u;         // hi = trunc
  u32 lo = (u32)f2bf_rne(v - __uint_as_float(uh));   // lo = RNE residual
  return uh | lo;
}
__device__ __forceinline__ void dev_st_u32x2(u32* p, u32x2 v) {
  asm volatile("global_store_dwordx2 %0, %1, off sc0 sc1" :: "v"(p), "v"(v) : "memory");
}
// unpack 8 packed u32 (2 x4) -> hi/lo bf16 fragments (col order preserved)
__device__ __forceinline__ void unpack8(u32x4 a, u32x4 b, s16x8& hi, s16x8& lo) {
  u32x4 H, L;
  H[0] = __builtin_amdgcn_perm(a[1], a[0], HISEL);
  H[1] = __builtin_amdgcn_perm(a[3], a[2], HISEL);
  H[2] = __builtin_amdgcn_perm(b[1], b[0], HISEL);
  H[3] = __builtin_amdgcn_perm(b[3], b[2], HISEL);
  L[0] = __builtin_amdgcn_perm(a[1], a[0], LOSEL);
  L[1] = __builtin_amdgcn_perm(a[3], a[2], LOSEL);
  L[2] = __builtin_amdgcn_perm(b[1], b[0], LOSEL);
  L[3] = __builtin_amdgcn_perm(b[3], b[2], LOSEL);
  hi = __builtin_bit_cast(s16x8, H);
  lo = __builtin_bit_cast(s16x8, L);
}

__global__ void lstm_zero_ws(u32* __restrict__ p) {
  int i = blockIdx.x * 256 + threadIdx.x;
  if (i < ZERO_INTS) p[i] = 0;
}

// ---------- x -> packed (hi|lo) u32 plane ----------
__global__ void lstm_xpack(const float* __restrict__ x, u32* __restrict__ xpk) {
  long i = ((long)blockIdx.x * 256 + threadIdx.x) * 4;
  if (i >= (long)XEL) return;
  f32x4 v = *(const f32x4*)(x + i);
  u32x4 o;
#pragma unroll
  for (int e = 0; e < 4; ++e) o[e] = packbf(v[e] * PKEEP);
  *(u32x4*)(xpk + i) = o;
}

// ---------- persistent recurrence ----------
// MODE: 0 = xpack planes, 1 = direct fp32 convert
template <int MODE>
__device__ __forceinline__ void recur_body(
    const float* __restrict__ x, const int* __restrict__ lens,
    const float* __restrict__ W, const float* __restrict__ U,
    const float* __restrict__ bih, const float* __restrict__ bhh,
    float* __restrict__ out, u32* __restrict__ hbuf, const u32* __restrict__ xpk) {
  const int wg = blockIdx.x, tid = threadIdx.x;
  const int m = wg >> 4, n = wg & 15;          // row-group, hcol-block
  const int lane = tid & 63, wave = tid >> 6;  // wave = gate index
  const int n16 = lane & 15, kgrp = lane >> 4;

  // ---- persistent B fragments: wave's 16 cols = gate `wave`, hcols n*16+n16
  const int grow = wave * HID + n * 16 + n16;
  s16x8 BUh[8], BUl[8], BWh[8], BWl[8];
#pragma unroll
  for (int ks = 0; ks < 8; ++ks) {
    const int base = grow * DIM + ks * 32 + kgrp * 8;
#pragma unroll
    for (int e = 0; e < 8; ++e) {
      float uv = U[base + e];
      u16 uh = f2bf_rne(uv);
      BUh[ks][e] = (short)uh;
      BUl[ks][e] = (short)f2bf_rne(uv - bf2f(uh));
      float wv = W[base + e];
      u16 wh = f2bf_rne(wv);
      BWh[ks][e] = (short)wh;
      BWl[ks][e] = (short)f2bf_rne(wv - bf2f(wh));
    }
  }

  // ---- cell mapping: 1 cell/thread
  const int crow = tid >> 4;          // row within group (0..15)
  const int chc  = tid & 15;          // hcol within block (0..15)
  const int gb   = m * RPG + crow;    // global batch row
  const int ghc  = n * 16 + chc;      // global hcol
  const float bi  = bih[0 * HID + ghc] + bhh[0 * HID + ghc];
  const float bfo = bih[1 * HID + ghc] + bhh[1 * HID + ghc];
  const float bg  = bih[2 * HID + ghc] + bhh[2 * HID + ghc];
  const float bo  = bih[3 * HID + ghc] + bhh[3 * HID + ghc];
  const int len = lens[gb];
  float hreg = 0.0f, creg = 0.0f;

  __shared__ u32 hstage[RPG * HID];     // 16KB, XOR-swizzled packed h
  __shared__ float glds[4][16][17];     // gate tiles

  for (int t = 0; t < T_STEPS; ++t) {
    const int par = t & 1;

    // ---- preload x fragments for THIS step (normal cached; hides under poll)
    u32x4 xa[8][2];
    f32x4 xf[8][2];
    if constexpr (MODE == 0) {
      const u32* xp = xpk + ((long)t * BATCH + m * RPG + n16) * DIM + kgrp * 8;
#pragma unroll
      for (int ks = 0; ks < 8; ++ks) {
        xa[ks][0] = *(const u32x4*)(xp + ks * 32);
        xa[ks][1] = *(const u32x4*)(xp + ks * 32 + 4);
      }
    } else {
      const float* xr = x + ((long)t * BATCH + m * RPG + n16) * DIM + kgrp * 8;
#pragma unroll
      for (int ks = 0; ks < 8; ++ks) {
        xf[ks][0] = *(const f32x4*)(xr + ks * 32);
        xf[ks][1] = *(const f32x4*)(xr + ks * 32 + 4);
      }
    }

    // ---- poll+load h pairs: tag==t in the same 16B read => h fresh
    u32x4 P[8];
    {
      const u32* rb = hbuf + par * PLANE_U32 + m * REGION_U32 + crow * (HID * 2) + chc * 32;
      for (;;) {
#pragma unroll
        for (int j = 0; j < 8; ++j)
          asm volatile("global_load_dwordx4 %0, %1, off sc0 sc1"
                       : "=v"(P[j]) : "v"(rb + j * 4) : "memory");
        asm volatile("s_waitcnt vmcnt(0)" ::: "memory");
        if (t == 0) break;  // plane zeroed: h=0, no wait
        bool stale = false;
#pragma unroll
        for (int j = 0; j < 8; ++j)
          stale |= (P[j][1] != (u32)t) || (P[j][3] != (u32)t);
        if (!__any(stale)) break;
      }
    }
    __builtin_amdgcn_sched_barrier(0);

    // ---- stage h (packed u32) to swizzled LDS
    {
      u32 hv[16];
#pragma unroll
      for (int j = 0; j < 8; ++j) { hv[2 * j] = P[j][0]; hv[2 * j + 1] = P[j][2]; }
      const int c0 = chc * 16;
#pragma unroll
      for (int q = 0; q < 4; ++q) {
        const int byte = ((crow * HID + c0 + q * 4) * 4) ^ ((crow & 15) << 4);
        u32x4 v = {hv[4 * q], hv[4 * q + 1], hv[4 * q + 2], hv[4 * q + 3]};
        *(u32x4*)((char*)hstage + byte) = v;
      }
    }
    __syncthreads();

    // ---- gate GEMM: two independent acc chains (h-part, x-part)
    f32x4 ah = {0.f, 0.f, 0.f, 0.f}, ax = {0.f, 0.f, 0.f, 0.f};
#pragma unroll
    for (int ks = 0; ks < 8; ++ks) {
      const int b0 = ((n16 * HID + kgrp * 8 + ks * 32) * 4) ^ ((n16 & 15) << 4);
      const int b1 = (((n16 * HID + kgrp * 8 + ks * 32) * 4) + 16) ^ ((n16 & 15) << 4);
      u32x4 h0 = *(const u32x4*)((const char*)hstage + b0);
      u32x4 h1 = *(const u32x4*)((const char*)hstage + b1);
      s16x8 Hh, Hl;
      unpack8(h0, h1, Hh, Hl);
      s16x8 Xh, Xl;
      if constexpr (MODE == 0) {
        unpack8(xa[ks][0], xa[ks][1], Xh, Xl);
      } else {
#pragma unroll
        for (int e = 0; e < 8; ++e) {
          float v = (e < 4 ? xf[ks][0][e] : xf[ks][1][e - 4]) * PKEEP;
          unsigned hb = __float_as_uint(v) & 0xFFFF0000u;
          Xh[e] = (short)(hb >> 16);
          Xl[e] = (short)(u16)(__float_as_uint(v - __uint_as_float(hb)) >> 16);
        }
      }
      ah = __builtin_amdgcn_mfma_f32_16x16x32_bf16(Hh, BUh[ks], ah, 0, 0, 0);
      ax = __builtin_amdgcn_mfma_f32_16x16x32_bf16(Xh, BWh[ks], ax, 0, 0, 0);
      ah = __builtin_amdgcn_mfma_f32_16x16x32_bf16(Hl, BUh[ks], ah, 0, 0, 0);
      ax = __builtin_amdgcn_mfma_f32_16x16x32_bf16(Xl, BWh[ks], ax, 0, 0, 0);
      ah = __builtin_amdgcn_mfma_f32_16x16x32_bf16(Hh, BUl[ks], ah, 0, 0, 0);
      ax = __builtin_amdgcn_mfma_f32_16x16x32_bf16(Xh, BWl[ks], ax, 0, 0, 0);
    }

    // ---- gate tile -> LDS (D layout: col=lane&15, row=(lane>>4)*4+r)
#pragma unroll
    for (int r = 0; r < 4; ++r) glds[wave][kgrp * 4 + r][n16] = ah[r] + ax[r];
    __syncthreads();

    // ---- cell update (1 cell/thread)
    float gi = glds[0][crow][chc] + bi;
    float gf = glds[1][crow][chc] + bfo;
    float gg = glds[2][crow][chc] + bg;
    float go = glds[3][crow][chc] + bo;
    float it = sigm(gi), ft = sigm(gf), ot = sigm(go);
    float gt = tanh_f(gg);
    float cnew = ft * creg + it * gt;
    float hnew = ot * tanh_f(cnew);
    const bool act = (t < len);
    if (act) { creg = cnew; hreg = hnew; }

    // ---- publish: ONE atomic dwordx2 (packed h, tag t+1); no barrier needed
    u32x2 pv = {packbf(hreg * PKEEP), (u32)(t + 1)};
    dev_st_u32x2(hbuf + (par ^ 1) * PLANE_U32 + m * REGION_U32 + crow * (HID * 2) + ghc * 2, pv);

    // ---- out store off the critical path
    out[(long)t * (BATCH * HID) + gb * HID + ghc] = act ? hnew : 0.0f;
  }

  // ---- epilogue: h_n, c_n
  out[(long)T_STEPS * (BATCH * HID) + gb * HID + ghc] = hreg;
  out[(long)T_STEPS * (BATCH * HID) + BATCH * HID + gb * HID + ghc] = creg;
}

#define RECUR_PARAMS                                                          \
  const float* __restrict__ x, const int* __restrict__ lens,                  \
  const float* __restrict__ W, const float* __restrict__ U,                   \
  const float* __restrict__ bih, const float* __restrict__ bhh,               \
  float* __restrict__ out, u32* __restrict__ hbuf, const u32* __restrict__ xpk
#define RECUR_ARGS x, lens, W, U, bih, bhh, out, hbuf, xpk

__global__ __launch_bounds__(256, 1) void lstm_recur_v5_xpk(RECUR_PARAMS) { recur_body<0>(RECUR_ARGS); }
__global__ __launch_bounds__(256, 1) void lstm_recur_v5_dir(RECUR_PARAMS) { recur_body<1>(RECUR_ARGS); }

extern "C" void kernel_launch(void* const* d_in, const int* in_sizes, int n_in,
                              void* d_out, int out_size, void* d_ws, size_t ws_size,
                              hipStream_t stream) {
  const float* x   = (const float*)d_in[0];
  const int*   len = (const int*)d_in[1];
  const float* W   = (const float*)d_in[2];
  const float* U   = (const float*)d_in[3];
  const float* bih = (const float*)d_in[4];
  const float* bhh = (const float*)d_in[5];
  float* out = (float*)d_out;
  char*  ws  = (char*)d_ws;
  u32* hbuf = (u32*)(ws + HBUF_OFF);
  char* big = ws + BIG_OFF;

  lstm_zero_ws<<<dim3((ZERO_INTS + 255) / 256), dim3(256), 0, stream>>>(hbuf);

  const size_t need_xp = (size_t)BIG_OFF + (size_t)XEL * 4;  // ~129MB
  if (ws_size >= need_xp) {
    u32* xpk = (u32*)big;
    lstm_xpack<<<dim3(32768), dim3(256), 0, stream>>>(x, xpk);
    lstm_recur_v5_xpk<<<dim3(64), dim3(256), 0, stream>>>(x, len, W, U, bih, bhh, out, hbuf, xpk);
  } else {
    lstm_recur_v5_dir<<<dim3(64), dim3(256), 0, stream>>>(x, len, W, U, bih, bhh, out, hbuf, nullptr);
  }
}